// Round 5
// baseline (627.798 us; speedup 1.0000x reference)
//
#include <hip/hip_runtime.h>
#include <math.h>
#include <stdint.h>
#include <stddef.h>

#define NB 8
#define NC 256
#define NN 4096
#define BN_EPS 1e-5f
#define LOG2E 1.44269504088896340736f

typedef unsigned short u16;
typedef __attribute__((ext_vector_type(4))) unsigned short u16x4;
typedef __attribute__((ext_vector_type(8))) short bf16x8;   // 8 bf16 = 4 VGPR
typedef __attribute__((ext_vector_type(4))) float f32x4;

static __device__ __forceinline__ float4 ld4(const float* p) { return *(const float4*)p; }
static __device__ __forceinline__ void st4(float* p, float4 v) { *(float4*)p = v; }
static __device__ __forceinline__ u16 f2bf(float f) {
  uint32_t u = __float_as_uint(f);
  return (u16)((u + 0x7FFFu + ((u >> 16) & 1u)) >> 16);   // RNE
}

// ---------------------------------------------------------------------------
// Kernel 1: fused QKV 1x1-conv + BN + ReLU. fp32 GEMM, bf16 outputs.
//   R5: q-branch BN constants folded with log2e so attention can use exp2.
//   q_bf,k_bf : [B][N][32] bf16 ; v_bf : [B][C][N] bf16
// ---------------------------------------------------------------------------
__global__ __launch_bounds__(256) void qkv_fused(
    const float* __restrict__ x,
    const float* __restrict__ wq, const float* __restrict__ bq,
    const float* __restrict__ gq, const float* __restrict__ betaq,
    const float* __restrict__ mq, const float* __restrict__ vq,
    const float* __restrict__ wk, const float* __restrict__ bk,
    const float* __restrict__ gk, const float* __restrict__ betak,
    const float* __restrict__ mk, const float* __restrict__ vk,
    const float* __restrict__ wv, const float* __restrict__ bv,
    const float* __restrict__ gv, const float* __restrict__ betav,
    const float* __restrict__ mv, const float* __restrict__ vv,
    u16* __restrict__ q_bf, u16* __restrict__ k_bf, u16* __restrict__ v_bf)
{
  __shared__ __align__(16) float smem[8704];
  float* sX = smem;          // [32 c][128 n]
  float* sW = smem + 4096;   // [64 o][36]
  float* sT = smem;          // epilogue [128 n][68]

  const int tid   = threadIdx.x;
  const int bx    = blockIdx.x;
  const int b     = bx & 7;
  const int rem   = bx >> 3;
  const int ntile = rem & 31;
  const int otile = rem >> 5;
  const int n0    = ntile * 128;
  const int o0    = otile * 64;

  const int to = tid >> 4;
  const int tn = tid & 15;

  float acc[4][2][4];
#pragma unroll
  for (int j = 0; j < 4; ++j)
#pragma unroll
    for (int r = 0; r < 2; ++r)
#pragma unroll
      for (int e = 0; e < 4; ++e) acc[j][r][e] = 0.f;

  const float* xb = x + (size_t)b * NC * NN + n0;

  for (int ch = 0; ch < 8; ++ch) {
    const int c0 = ch * 32;
#pragma unroll
    for (int p = 0; p < 4; ++p) {
      int f = p * 256 + tid;
      int row = f >> 5, col4 = f & 31;
      st4(sX + row * 128 + col4 * 4, ld4(xb + (size_t)(c0 + row) * NN + col4 * 4));
    }
#pragma unroll
    for (int p = 0; p < 2; ++p) {
      int f = p * 256 + tid;
      int row = f >> 3, col4 = f & 7;
      int o = o0 + row;
      const float* wrow;
      if (o < 32)      wrow = wq + o * NC;
      else if (o < 64) wrow = wk + (o - 32) * NC;
      else             wrow = wv + (o - 64) * NC;
      st4(sW + row * 36 + col4 * 4, ld4(wrow + c0 + col4 * 4));
    }
    __syncthreads();

    for (int cc = 0; cc < 8; ++cc) {
      float wr[4][4];
#pragma unroll
      for (int j = 0; j < 4; ++j) {
        float4 t = ld4(sW + (to * 4 + j) * 36 + cc * 4);
        wr[j][0] = t.x; wr[j][1] = t.y; wr[j][2] = t.z; wr[j][3] = t.w;
      }
      float xr[4][2][4];
#pragma unroll
      for (int lc = 0; lc < 4; ++lc)
#pragma unroll
        for (int r = 0; r < 2; ++r) {
          float4 t = ld4(sX + (cc * 4 + lc) * 128 + tn * 4 + r * 64);
          xr[lc][r][0] = t.x; xr[lc][r][1] = t.y; xr[lc][r][2] = t.z; xr[lc][r][3] = t.w;
        }
#pragma unroll
      for (int j = 0; j < 4; ++j)
#pragma unroll
        for (int lc = 0; lc < 4; ++lc)
#pragma unroll
          for (int r = 0; r < 2; ++r)
#pragma unroll
            for (int e = 0; e < 4; ++e)
              acc[j][r][e] = fmaf(wr[j][lc], xr[lc][r][e], acc[j][r][e]);
    }
    __syncthreads();
  }

  if (otile == 0) {
#pragma unroll
    for (int j = 0; j < 4; ++j) {
      int o = to * 4 + j;
      float bias, g, beta, mean, var;
      if (o < 32) { int d = o;      bias = bq[d]; g = gq[d]; beta = betaq[d]; mean = mq[d]; var = vq[d]; }
      else        { int d = o - 32; bias = bk[d]; g = gk[d]; beta = betak[d]; mean = mk[d]; var = vk[d]; }
      float alpha = g * rsqrtf(var + BN_EPS);
      float delta = (bias - mean) * alpha + beta;
      if (o < 32) { alpha *= LOG2E; delta *= LOG2E; }   // q pre-scaled for exp2 softmax
#pragma unroll
      for (int r = 0; r < 2; ++r)
#pragma unroll
        for (int e = 0; e < 4; ++e) {
          float y = fmaxf(fmaf(acc[j][r][e], alpha, delta), 0.f);
          int n = tn * 4 + r * 64 + e;
          sT[n * 68 + to * 4 + j] = y;
        }
    }
    __syncthreads();
    const size_t nrow = (size_t)b * NN + n0;
#pragma unroll
    for (int p = 0; p < 8; ++p) {
      int f = p * 256 + tid;
      int n = f >> 4, col4 = f & 15;
      float4 t = ld4(sT + n * 68 + col4 * 4);
      u16x4 h = { f2bf(t.x), f2bf(t.y), f2bf(t.z), f2bf(t.w) };
      if (col4 < 8) *(u16x4*)(q_bf + (nrow + n) * 32 + col4 * 4) = h;
      else          *(u16x4*)(k_bf + (nrow + n) * 32 + (col4 - 8) * 4) = h;
    }
  } else {
#pragma unroll
    for (int j = 0; j < 4; ++j) {
      int c = (otile - 1) * 64 + to * 4 + j;
      float alpha = gv[c] * rsqrtf(vv[c] + BN_EPS);
      float delta = (bv[c] - mv[c]) * alpha + betav[c];
#pragma unroll
      for (int r = 0; r < 2; ++r) {
        u16x4 h;
#pragma unroll
        for (int e = 0; e < 4; ++e)
          h[e] = f2bf(fmaxf(fmaf(acc[j][r][e], alpha, delta), 0.f));
        int n = n0 + tn * 4 + r * 64;
        *(u16x4*)(v_bf + ((size_t)b * NC + c) * NN + n) = h;
      }
    }
  }
}

// ---------------------------------------------------------------------------
// Kernel 2: MFMA flash attention, R5: work-split softmax (no redundancy).
//   WG = 4 waves, 32 q-rows. Wave w owns j-quarter [16w,16w+16): 1 K-load +
//   2 S-MFMAs per iter. Row max/sum: 4-stage shfl within 16-lane groups,
//   cross-wave combine via sMx/sLx in LDS. 2 barriers/iter. P tile (bf16,
//   XOR-swizzled) shared in LDS; each wave does PV for its 64 channels.
//   Q pre-scaled by log2e -> softmax uses exp2f (1 instr).
//   V-frags + next K prefetched under the softmax exchange.
// ---------------------------------------------------------------------------
__global__ __launch_bounds__(256, 4) void attn_mfma(
    const u16* __restrict__ q_bf, const u16* __restrict__ k_bf,
    const u16* __restrict__ v_bf, const float* __restrict__ x,
    const float* __restrict__ gamma, float* __restrict__ out)
{
  __shared__ u16 sP[32 * 64];        // swizzled P tile (32 i x 64 j)
  __shared__ float sMx[32 * 4];      // per-quarter row maxes
  __shared__ float sLx[32 * 4];      // per-quarter row sums

  const int tid = threadIdx.x;
  const int w   = tid >> 6;
  const int l   = tid & 63;
  const int xl  = l & 15;
  const int g   = l >> 4;
  const int b   = blockIdx.x & 7;
  const int rt  = blockIdx.x >> 3;   // 0..127
  const int i0  = rt * 32;

  const u16* qb  = q_bf + ((size_t)b * NN + i0) * 32;
  const u16* kb0 = k_bf + (size_t)b * NN * 32 + (size_t)(16 * w + xl) * 32 + 8 * g;
  const u16* vb  = v_bf + ((size_t)b * NC + w * 64) * NN;

  // Q A-frags: lane holds Q[i = blk*16+xl][k = 8g..8g+7]
  bf16x8 qf[2];
  qf[0] = *(const bf16x8*)(qb + (size_t)xl * 32 + 8 * g);
  qf[1] = *(const bf16x8*)(qb + (size_t)(16 + xl) * 32 + 8 * g);

  f32x4 acc[2][4];
#pragma unroll
  for (int blk = 0; blk < 2; ++blk)
#pragma unroll
    for (int ct = 0; ct < 4; ++ct)
      acc[blk][ct] = (f32x4){0.f, 0.f, 0.f, 0.f};

  float mr[2][4], lr[2][4];
#pragma unroll
  for (int blk = 0; blk < 2; ++blk)
#pragma unroll
    for (int r = 0; r < 4; ++r) { mr[blk][r] = -INFINITY; lr[blk][r] = 0.f; }

  bf16x8 kf = *(const bf16x8*)kb0;

  for (int jt64 = 0; jt64 < 64; ++jt64) {
    const int j0 = jt64 * 64;

    // S quarter: rows 32, cols 16w..16w+16
    f32x4 s0 = __builtin_amdgcn_mfma_f32_16x16x32_bf16(qf[0], kf, (f32x4){0.f,0.f,0.f,0.f}, 0, 0, 0);
    f32x4 s1 = __builtin_amdgcn_mfma_f32_16x16x32_bf16(qf[1], kf, (f32x4){0.f,0.f,0.f,0.f}, 0, 0, 0);

    // prefetch next K quarter (last iter reads into v_bf region: harmless, unused)
    bf16x8 kf_next = *(const bf16x8*)(kb0 + (size_t)(j0 + 64) * 32);

    // prefetch V frags for this iter (latency hides under softmax exchange)
    bf16x8 vf[2][4];
#pragma unroll
    for (int jt2 = 0; jt2 < 2; ++jt2)
#pragma unroll
      for (int ct = 0; ct < 4; ++ct)
        vf[jt2][ct] = *(const bf16x8*)(vb + (size_t)(ct * 16 + xl) * NN + j0 + jt2 * 32 + 8 * g);

    // quarter row-max over the 16 cols (lanes xl within group g)
    float q0[4], q1[4];
#pragma unroll
    for (int r = 0; r < 4; ++r) { q0[r] = s0[r]; q1[r] = s1[r]; }
#pragma unroll
    for (int msk = 1; msk < 16; msk <<= 1) {
#pragma unroll
      for (int r = 0; r < 4; ++r) {
        q0[r] = fmaxf(q0[r], __shfl_xor(q0[r], msk));
        q1[r] = fmaxf(q1[r], __shfl_xor(q1[r], msk));
      }
    }
    if (xl == 0) {
#pragma unroll
      for (int r = 0; r < 4; ++r) {
        sMx[(4 * g + r) * 4 + w]      = q0[r];
        sMx[(16 + 4 * g + r) * 4 + w] = q1[r];
      }
    }
    __syncthreads();

    // combine tile max; gated rescale
    float t0[4], t1[4];
    bool need = false;
#pragma unroll
    for (int r = 0; r < 4; ++r) {
      float4 m4 = *(const float4*)&sMx[(4 * g + r) * 4];
      t0[r] = fmaxf(fmaxf(m4.x, m4.y), fmaxf(m4.z, m4.w));
      need = need || (t0[r] > mr[0][r]);
      float4 n4 = *(const float4*)&sMx[(16 + 4 * g + r) * 4];
      t1[r] = fmaxf(fmaxf(n4.x, n4.y), fmaxf(n4.z, n4.w));
      need = need || (t1[r] > mr[1][r]);
    }
    if (__any(need)) {
#pragma unroll
      for (int r = 0; r < 4; ++r) {
        float mn0 = fmaxf(mr[0][r], t0[r]);
        float sc0 = exp2f(mr[0][r] - mn0);
        mr[0][r] = mn0; lr[0][r] *= sc0;
        float mn1 = fmaxf(mr[1][r], t1[r]);
        float sc1 = exp2f(mr[1][r] - mn1);
        mr[1][r] = mn1; lr[1][r] *= sc1;
#pragma unroll
        for (int ct = 0; ct < 4; ++ct) {
          acc[0][ct][r] *= sc0;
          acc[1][ct][r] *= sc1;
        }
      }
    }

    // P = exp2(s - m), write quarter to swizzled sP, partial row sums
    float ts0[4], ts1[4];
#pragma unroll
    for (int r = 0; r < 4; ++r) {
      float p0 = exp2f(s0[r] - mr[0][r]);
      ts0[r] = p0;
      int row0 = 4 * g + r;
      sP[row0 * 64 + ((16 * w + xl) ^ ((row0 & 7) << 3))] = f2bf(p0);
      float p1 = exp2f(s1[r] - mr[1][r]);
      ts1[r] = p1;
      int row1 = 16 + 4 * g + r;
      sP[row1 * 64 + ((16 * w + xl) ^ ((row1 & 7) << 3))] = f2bf(p1);
    }
#pragma unroll
    for (int msk = 1; msk < 16; msk <<= 1) {
#pragma unroll
      for (int r = 0; r < 4; ++r) {
        ts0[r] += __shfl_xor(ts0[r], msk);
        ts1[r] += __shfl_xor(ts1[r], msk);
      }
    }
    if (xl == 0) {
#pragma unroll
      for (int r = 0; r < 4; ++r) {
        sLx[(4 * g + r) * 4 + w]      = ts0[r];
        sLx[(16 + 4 * g + r) * 4 + w] = ts1[r];
      }
    }
    __syncthreads();

#pragma unroll
    for (int r = 0; r < 4; ++r) {
      float4 l4 = *(const float4*)&sLx[(4 * g + r) * 4];
      lr[0][r] += (l4.x + l4.y) + (l4.z + l4.w);
      float4 k4 = *(const float4*)&sLx[(16 + 4 * g + r) * 4];
      lr[1][r] += (k4.x + k4.y) + (k4.z + k4.w);
    }

    // PV for this wave's 64 channels
#pragma unroll
    for (int jt2 = 0; jt2 < 2; ++jt2) {
      int row0 = xl, row1 = 16 + xl;
      bf16x8 pf0 = *(const bf16x8*)(sP + row0 * 64 + ((jt2 * 32 + 8 * g) ^ ((row0 & 7) << 3)));
      bf16x8 pf1 = *(const bf16x8*)(sP + row1 * 64 + ((jt2 * 32 + 8 * g) ^ ((row1 & 7) << 3)));
#pragma unroll
      for (int ct = 0; ct < 4; ++ct) {
        acc[0][ct] = __builtin_amdgcn_mfma_f32_16x16x32_bf16(pf0, vf[jt2][ct], acc[0][ct], 0, 0, 0);
        acc[1][ct] = __builtin_amdgcn_mfma_f32_16x16x32_bf16(pf1, vf[jt2][ct], acc[1][ct], 0, 0, 0);
      }
    }

    kf = kf_next;
  }

  // ---- epilogue: out = gamma * acc/l + x, direct float4 RMW ----
  float linv[2][4];
#pragma unroll
  for (int blk = 0; blk < 2; ++blk)
#pragma unroll
    for (int r = 0; r < 4; ++r) linv[blk][r] = 1.f / lr[blk][r];

  const float gm = gamma[0];
#pragma unroll
  for (int blk = 0; blk < 2; ++blk)
#pragma unroll
    for (int ct = 0; ct < 4; ++ct) {
      int c = w * 64 + ct * 16 + xl;
      size_t off = ((size_t)b * NC + c) * NN + i0 + blk * 16 + 4 * g;
      float4 xv = ld4(x + off);
      float4 o4;
      o4.x = fmaf(gm, acc[blk][ct][0] * linv[blk][0], xv.x);
      o4.y = fmaf(gm, acc[blk][ct][1] * linv[blk][1], xv.y);
      o4.z = fmaf(gm, acc[blk][ct][2] * linv[blk][2], xv.z);
      o4.w = fmaf(gm, acc[blk][ct][3] * linv[blk][3], xv.w);
      st4(out + off, o4);
    }
}

// ---------------------------------------------------------------------------
extern "C" void kernel_launch(void* const* d_in, const int* in_sizes, int n_in,
                              void* d_out, int out_size, void* d_ws, size_t ws_size,
                              hipStream_t stream) {
  const float* x     = (const float*)d_in[0];
  const float* wq    = (const float*)d_in[1];
  const float* bq    = (const float*)d_in[2];
  const float* gq    = (const float*)d_in[3];
  const float* betaq = (const float*)d_in[4];
  const float* mq    = (const float*)d_in[5];
  const float* vq    = (const float*)d_in[6];
  const float* wk    = (const float*)d_in[7];
  const float* bk    = (const float*)d_in[8];
  const float* gk    = (const float*)d_in[9];
  const float* betak = (const float*)d_in[10];
  const float* mk    = (const float*)d_in[11];
  const float* vk    = (const float*)d_in[12];
  const float* wv    = (const float*)d_in[13];
  const float* bv    = (const float*)d_in[14];
  const float* gv    = (const float*)d_in[15];
  const float* betav = (const float*)d_in[16];
  const float* mv    = (const float*)d_in[17];
  const float* vv    = (const float*)d_in[18];
  const float* gamma = (const float*)d_in[19];
  float* out = (float*)d_out;

  u16* q_bf = (u16*)d_ws;
  u16* k_bf = q_bf + (size_t)NB * NN * 32;
  u16* v_bf = k_bf + (size_t)NB * NN * 32;

  qkv_fused<<<dim3(1280), dim3(256), 0, stream>>>(
      x, wq, bq, gq, betaq, mq, vq,
      wk, bk, gk, betak, mk, vk,
      wv, bv, gv, betav, mv, vv,
      q_bf, k_bf, v_bf);

  attn_mfma<<<dim3(1024), dim3(256), 0, stream>>>(q_bf, k_bf, v_bf, x, gamma, out);
}